// Round 5
// baseline (1754.391 us; speedup 1.0000x reference)
//
#include <hip/hip_runtime.h>
#include <hip/hip_bf16.h>
#include <limits.h>

#define NUM_NODES 100000
#define OUT_CH 64
#define NUM_EDGES 3200000
#define BROWS 128                 // rows per bucket
#define NBUCK 782                 // ceil(100000/128); 782*128 = 100096
#define NSUB 8                    // sub-cursors per bucket (cuts same-address contention)
#define NSS (NBUCK * NSUB)        // 6256 counters
#define PGRID 3125                // 3125 blk * 256 thr * 4 edges = 3,200,000 exactly

// ---------- K1: min of edge_index[0] (vectorized) ----------
__global__ void LINK_62689342652831_min_kernel(const int* __restrict__ rows,
                                               int* __restrict__ minp) {
    int t = blockIdx.x * blockDim.x + threadIdx.x;  // 800000 threads, 4 edges each
    const int4* r4 = (const int4*)rows;
    int4 v = r4[t];
    int m = min(min(v.x, v.y), min(v.z, v.w));
    for (int off = 32; off > 0; off >>= 1) m = min(m, __shfl_xor(m, off, 64));
    if ((threadIdx.x & 63) == 0) atomicMin(minp, m);
}

// ---------- K2: transpose W [64][N] -> Wtb [N][64] bf16 ----------
__global__ void LINK_62689342652831_transpose_kernel(const float* __restrict__ W,
                                                     unsigned short* __restrict__ Wtb) {
    __shared__ float tile[64][65];
    int n0 = blockIdx.x * 64;
    int tx = threadIdx.x & 63;
    int ty = threadIdx.x >> 6;  // 0..3
    for (int c = ty; c < 64; c += 4) {
        int n = n0 + tx;
        tile[c][tx] = (n < NUM_NODES) ? W[(size_t)c * NUM_NODES + n] : 0.0f;
    }
    __syncthreads();
    for (int i = ty; i < 64; i += 4) {
        int n = n0 + i;
        if (n < NUM_NODES) {
            __hip_bfloat16 b = __float2bfloat16(tile[tx][i]);
            Wtb[(size_t)n * OUT_CH + tx] = *(unsigned short*)&b;
        }
    }
}

// ---------- K3: histogram over (bucket, sub) — sub tied to blockIdx ----------
__global__ __launch_bounds__(256) void LINK_62689342652831_hist_kernel(
    const int* __restrict__ rows, const int* __restrict__ minp,
    int* __restrict__ ghist) {
    __shared__ int h[NBUCK];
    for (int i = threadIdx.x; i < NBUCK; i += 256) h[i] = 0;
    __syncthreads();
    int minv = *minp;
    int sub = blockIdx.x & (NSUB - 1);
    int t = blockIdx.x * 256 + threadIdx.x;
    const int4* r4 = (const int4*)rows;
    int4 v = r4[t];
    atomicAdd(&h[(unsigned)(v.x - minv) >> 7], 1);
    atomicAdd(&h[(unsigned)(v.y - minv) >> 7], 1);
    atomicAdd(&h[(unsigned)(v.z - minv) >> 7], 1);
    atomicAdd(&h[(unsigned)(v.w - minv) >> 7], 1);
    __syncthreads();
    for (int i = threadIdx.x; i < NBUCK; i += 256)
        if (h[i]) atomicAdd(&ghist[i * NSUB + sub], h[i]);
}

// ---------- K4: scan of 6256 counters (single block, 8/thread) ----------
__global__ __launch_bounds__(1024) void LINK_62689342652831_scan_kernel(
    const int* __restrict__ cnt, int* __restrict__ sstart, int* __restrict__ cursor) {
    __shared__ int ss[1024];
    int t = threadIdx.x;
    int base = t * 8;
    int v[8], p[8];
#pragma unroll
    for (int k = 0; k < 8; ++k) v[k] = (base + k < NSS) ? cnt[base + k] : 0;
    p[0] = v[0];
#pragma unroll
    for (int k = 1; k < 8; ++k) p[k] = p[k - 1] + v[k];
    ss[t] = p[7];
    __syncthreads();
    for (int off = 1; off < 1024; off <<= 1) {
        int x = (t >= off) ? ss[t - off] : 0;
        __syncthreads();
        ss[t] += x;
        __syncthreads();
    }
    int texcl = ss[t] - p[7];
#pragma unroll
    for (int k = 0; k < 8; ++k) {
        if (base + k < NSS) {
            int ex = texcl + (k ? p[k - 1] : 0);
            sstart[base + k] = ex;
            cursor[base + k] = ex;
        }
    }
    if (t == 1023) sstart[NSS] = ss[1023];
}

// ---------- K5: partition edges into buckets as packed (lr<<17 | col) ----------
__global__ __launch_bounds__(256) void LINK_62689342652831_part_kernel(
    const int* __restrict__ rows, const int* __restrict__ cols,
    const int* __restrict__ minp, int* __restrict__ cursor,
    unsigned int* __restrict__ packed) {
    int minv = *minp;
    int sub = blockIdx.x & (NSUB - 1);
    int t = blockIdx.x * 256 + threadIdx.x;
    const int4* r4 = (const int4*)rows;
    const int4* c4 = (const int4*)cols;
    int4 rv = r4[t];
    int4 cv = c4[t];
#pragma unroll
    for (int k = 0; k < 4; ++k) {
        int r = ((k == 0) ? rv.x : (k == 1) ? rv.y : (k == 2) ? rv.z : rv.w) - minv;
        int c = (k == 0) ? cv.x : (k == 1) ? cv.y : (k == 2) ? cv.z : cv.w;
        int b = (unsigned)r >> 7;
        int lr = r & (BROWS - 1);
        int pos = atomicAdd(&cursor[b * NSUB + sub], 1);
        packed[pos] = ((unsigned)lr << 17) | (unsigned)c;
    }
}

// ---------- K6: per-bucket SpMM in LDS + fused bias/log_softmax ----------
__global__ __launch_bounds__(512) void LINK_62689342652831_spmm_kernel(
    const unsigned int* __restrict__ packed, const int* __restrict__ sstart,
    const unsigned short* __restrict__ Wtb, const float* __restrict__ bias,
    float* __restrict__ out) {
    __shared__ float acc[BROWS * OUT_CH];  // 32 KB
    int lane = threadIdx.x & 63;
    int wid = __builtin_amdgcn_readfirstlane(threadIdx.x >> 6);  // 0..7, wave-uniform
#pragma unroll
    for (int i = threadIdx.x; i < BROWS * OUT_CH; i += 512) acc[i] = 0.0f;
    __syncthreads();

    int b = blockIdx.x;
    int s = sstart[b * NSUB];
    int e = sstart[(b + 1) * NSUB];
    int nfull = (e - s) >> 4;  // 16-edge chunks

    for (int c = wid; c < nfull; c += 8) {
        int i = s + c * 16;
        unsigned int p[16];
#pragma unroll
        for (int k = 0; k < 16; ++k) p[k] = packed[i + k];
        float v[16];
#pragma unroll
        for (int k = 0; k < 16; ++k)
            v[k] = __uint_as_float((unsigned int)Wtb[(p[k] & 0x1FFFF) * OUT_CH + lane] << 16);
#pragma unroll
        for (int k = 0; k < 16; ++k)
            atomicAdd(&acc[(p[k] >> 17) * OUT_CH + lane], v[k]);
    }
    if (wid == 0) {
        for (int i = s + nfull * 16; i < e; ++i) {
            unsigned int p = packed[i];
            float v = __uint_as_float((unsigned int)Wtb[(p & 0x1FFFF) * OUT_CH + lane] << 16);
            atomicAdd(&acc[(p >> 17) * OUT_CH + lane], v);
        }
    }
    __syncthreads();

    float bsv = bias[lane];
    int gbase = b * BROWS;
    for (int r = wid; r < BROWS; r += 8) {
        int gr = gbase + r;
        if (gr >= NUM_NODES) continue;
        float x = acc[r * OUT_CH + lane] + bsv;
        float m = x;
        for (int off = 32; off > 0; off >>= 1) m = fmaxf(m, __shfl_xor(m, off, 64));
        float ex = expf(x - m);
        float ssum = ex;
        for (int off = 32; off > 0; off >>= 1) ssum += __shfl_xor(ssum, off, 64);
        out[(size_t)gr * OUT_CH + lane] = x - m - logf(ssum);
    }
}

// ---------- fallback (round-1 path, direct W) ----------
__global__ void LINK_62689342652831_minf_kernel(const int* __restrict__ rows, int n,
                                                int* __restrict__ minp) {
    int tid = blockIdx.x * blockDim.x + threadIdx.x;
    int stride = gridDim.x * blockDim.x;
    int m = INT_MAX;
    for (int i = tid; i < n; i += stride) m = min(m, rows[i]);
    for (int off = 32; off > 0; off >>= 1) m = min(m, __shfl_xor(m, off, 64));
    if ((threadIdx.x & 63) == 0) atomicMin(minp, m);
}

__global__ void LINK_62689342652831_scatter_kernel(const int* __restrict__ rows,
                                                   const int* __restrict__ cols,
                                                   const float* __restrict__ W,
                                                   const int* __restrict__ minp,
                                                   float* __restrict__ out) {
    int lane = threadIdx.x & 63;
    int gw = (blockIdx.x * blockDim.x + threadIdx.x) >> 6;
    int nw = (gridDim.x * blockDim.x) >> 6;
    int minv = *minp;
    for (int e = gw; e < NUM_EDGES; e += nw) {
        int r = rows[e] - minv;
        int c = cols[e];
        float v = W[(size_t)lane * NUM_NODES + c];
        unsafeAtomicAdd(&out[(size_t)r * 64 + lane], v);
    }
}

__global__ void LINK_62689342652831_logsoftmax_kernel(float* __restrict__ out,
                                                      const float* __restrict__ bias) {
    int lane = threadIdx.x & 63;
    int gw = (blockIdx.x * blockDim.x + threadIdx.x) >> 6;
    int nw = (gridDim.x * blockDim.x) >> 6;
    float b = bias[lane];
    for (int r = gw; r < NUM_NODES; r += nw) {
        float x = out[(size_t)r * 64 + lane] + b;
        float m = x;
        for (int off = 32; off > 0; off >>= 1) m = fmaxf(m, __shfl_xor(m, off, 64));
        float e = expf(x - m);
        float s = e;
        for (int off = 32; off > 0; off >>= 1) s += __shfl_xor(s, off, 64);
        out[(size_t)r * 64 + lane] = x - m - logf(s);
    }
}

extern "C" void kernel_launch(void* const* d_in, const int* in_sizes, int n_in,
                              void* d_out, int out_size, void* d_ws, size_t ws_size,
                              hipStream_t stream) {
    const int* edges = (const int*)d_in[0];
    const int* rows = edges;
    const int* cols = edges + NUM_EDGES;
    const float* W = (const float*)d_in[1];
    const float* bias = (const float*)d_in[2];
    float* out = (float*)d_out;

    // workspace layout
    char* ws = (char*)d_ws;
    const size_t OFF_MIN = 0;                              // 4 B
    const size_t OFF_HIST = 256;                           // NSS*4 = 25024 B
    const size_t OFF_SSTART = 32 * 1024;                   // (NSS+1)*4 B
    const size_t OFF_CURSOR = 64 * 1024;                   // NSS*4 B
    const size_t OFF_PACKED = 96 * 1024;                   // 12.8 MB
    const size_t OFF_WTB = OFF_PACKED + (size_t)NUM_EDGES * 4;
    const size_t need = OFF_WTB + (size_t)NUM_NODES * OUT_CH * 2;

    int* minp = (int*)(ws + OFF_MIN);
    int* ghist = (int*)(ws + OFF_HIST);
    int* sstart = (int*)(ws + OFF_SSTART);
    int* cursor = (int*)(ws + OFF_CURSOR);
    unsigned int* packed = (unsigned int*)(ws + OFF_PACKED);
    unsigned short* Wtb = (unsigned short*)(ws + OFF_WTB);

    hipMemsetAsync(minp, 0x7f, sizeof(int), stream);

    if (ws_size >= need) {
        hipMemsetAsync(ghist, 0, (size_t)NSS * sizeof(int), stream);
        LINK_62689342652831_min_kernel<<<PGRID, 256, 0, stream>>>(rows, minp);
        LINK_62689342652831_transpose_kernel<<<(NUM_NODES + 63) / 64, 256, 0, stream>>>(W, Wtb);
        LINK_62689342652831_hist_kernel<<<PGRID, 256, 0, stream>>>(rows, minp, ghist);
        LINK_62689342652831_scan_kernel<<<1, 1024, 0, stream>>>(ghist, sstart, cursor);
        LINK_62689342652831_part_kernel<<<PGRID, 256, 0, stream>>>(rows, cols, minp,
                                                                   cursor, packed);
        LINK_62689342652831_spmm_kernel<<<NBUCK, 512, 0, stream>>>(packed, sstart, Wtb,
                                                                   bias, out);
    } else {
        LINK_62689342652831_minf_kernel<<<2048, 256, 0, stream>>>(rows, NUM_EDGES, minp);
        hipMemsetAsync(d_out, 0, (size_t)out_size * sizeof(float), stream);
        LINK_62689342652831_scatter_kernel<<<2048, 256, 0, stream>>>(rows, cols, W, minp, out);
        LINK_62689342652831_logsoftmax_kernel<<<4096, 256, 0, stream>>>(out, bias);
    }
}

// Round 6
// 323.990 us; speedup vs baseline: 5.4150x; 5.4150x over previous
//
#include <hip/hip_runtime.h>
#include <hip/hip_bf16.h>
#include <limits.h>

#define NUM_NODES 100000
#define OUT_CH 64
#define NUM_EDGES 3200000
#define BROWS 128                    // rows per bucket
#define NBUCK 782                    // ceil(100000/128); 782*128 = 100096
#define NPBLK 256                    // partition blocks
#define EPB (NUM_EDGES / NPBLK)      // 12500 edges per partition block
#define I4PB (EPB / 4)               // 3125 int4 per partition block
#define PGRID 3125                   // min kernel: 3125*256*4 = 3.2M
#define STAGECAP 6144                // LDS staging cap (avg 4092, sigma~64)

// ---------- K1: min of edge_index[0] (vectorized) ----------
__global__ void LINK_62689342652831_min_kernel(const int* __restrict__ rows,
                                               int* __restrict__ minp) {
    int t = blockIdx.x * blockDim.x + threadIdx.x;
    const int4* r4 = (const int4*)rows;
    int4 v = r4[t];
    int m = min(min(v.x, v.y), min(v.z, v.w));
    for (int off = 32; off > 0; off >>= 1) m = min(m, __shfl_xor(m, off, 64));
    if ((threadIdx.x & 63) == 0) atomicMin(minp, m);
}

// ---------- K2: transpose W [64][N] -> Wtb [N][64] bf16 ----------
__global__ void LINK_62689342652831_transpose_kernel(const float* __restrict__ W,
                                                     unsigned short* __restrict__ Wtb) {
    __shared__ float tile[64][65];
    int n0 = blockIdx.x * 64;
    int tx = threadIdx.x & 63;
    int ty = threadIdx.x >> 6;
    for (int c = ty; c < 64; c += 4) {
        int n = n0 + tx;
        tile[c][tx] = (n < NUM_NODES) ? W[(size_t)c * NUM_NODES + n] : 0.0f;
    }
    __syncthreads();
    for (int i = ty; i < 64; i += 4) {
        int n = n0 + i;
        if (n < NUM_NODES) {
            __hip_bfloat16 bv = __float2bfloat16(tile[tx][i]);
            Wtb[(size_t)n * OUT_CH + tx] = *(unsigned short*)&bv;
        }
    }
}

// ---------- K3: per-block bucket histogram -> hist2d[blk][bucket] ----------
__global__ __launch_bounds__(512) void LINK_62689342652831_hist2d_kernel(
    const int* __restrict__ rows, const int* __restrict__ minp,
    int* __restrict__ hist2d) {
    __shared__ int h[NBUCK];
    for (int i = threadIdx.x; i < NBUCK; i += 512) h[i] = 0;
    __syncthreads();
    int minv = *minp;
    int blk = blockIdx.x;
    const int4* r4 = (const int4*)rows;
    for (int i = threadIdx.x; i < I4PB; i += 512) {
        int4 v = r4[blk * I4PB + i];
        atomicAdd(&h[(unsigned)(v.x - minv) >> 7], 1);
        atomicAdd(&h[(unsigned)(v.y - minv) >> 7], 1);
        atomicAdd(&h[(unsigned)(v.z - minv) >> 7], 1);
        atomicAdd(&h[(unsigned)(v.w - minv) >> 7], 1);
    }
    __syncthreads();
    for (int i = threadIdx.x; i < NBUCK; i += 512) hist2d[blk * NBUCK + i] = h[i];
}

// ---------- K4a: per-bucket prefix over the 256 blocks (in-place) ----------
__global__ __launch_bounds__(512) void LINK_62689342652831_colscan_kernel(
    int* __restrict__ hist2d, int* __restrict__ totals) {
    int lane = threadIdx.x & 63;
    int wid = threadIdx.x >> 6;
    int b = blockIdx.x * 8 + wid;
    if (b >= NBUCK) return;
    int carry = 0;
    for (int rnd = 0; rnd < NPBLK / 64; ++rnd) {
        int blk = rnd * 64 + lane;
        int v = hist2d[blk * NBUCK + b];
        int x = v;
        for (int off = 1; off < 64; off <<= 1) {
            int y = __shfl_up(x, off, 64);
            if (lane >= off) x += y;
        }
        hist2d[blk * NBUCK + b] = x - v + carry;  // exclusive + carry
        carry += __shfl(x, 63, 64);
    }
    if (lane == 0) totals[b] = carry;
}

// ---------- K4b: scan bucket totals -> bstart[0..NBUCK] ----------
__global__ __launch_bounds__(1024) void LINK_62689342652831_bscan_kernel(
    const int* __restrict__ totals, int* __restrict__ bstart) {
    __shared__ int ss[1024];
    int t = threadIdx.x;
    int v = (t < NBUCK) ? totals[t] : 0;
    ss[t] = v;
    __syncthreads();
    for (int off = 1; off < 1024; off <<= 1) {
        int x = (t >= off) ? ss[t - off] : 0;
        __syncthreads();
        ss[t] += x;
        __syncthreads();
    }
    if (t < NBUCK) bstart[t] = ss[t] - v;
    if (t == NBUCK - 1) bstart[NBUCK] = ss[t];
}

// ---------- K5: partition edges into bucket regions (no global atomics) ----------
__global__ __launch_bounds__(512) void LINK_62689342652831_part_kernel(
    const int* __restrict__ rows, const int* __restrict__ cols,
    const int* __restrict__ minp, const int* __restrict__ hist2d,
    const int* __restrict__ bstart, unsigned int* __restrict__ packed) {
    __shared__ int offs_l[NBUCK];
    __shared__ int lcur[NBUCK];
    int blk = blockIdx.x;
    for (int i = threadIdx.x; i < NBUCK; i += 512) {
        offs_l[i] = bstart[i] + hist2d[blk * NBUCK + i];
        lcur[i] = 0;
    }
    __syncthreads();
    int minv = *minp;
    const int4* r4 = (const int4*)rows;
    const int4* c4 = (const int4*)cols;
    for (int i = threadIdx.x; i < I4PB; i += 512) {
        int4 rv = r4[blk * I4PB + i];
        int4 cv = c4[blk * I4PB + i];
#pragma unroll
        for (int k = 0; k < 4; ++k) {
            int r = ((k == 0) ? rv.x : (k == 1) ? rv.y : (k == 2) ? rv.z : rv.w) - minv;
            int c = (k == 0) ? cv.x : (k == 1) ? cv.y : (k == 2) ? cv.z : cv.w;
            int b = (unsigned)r >> 7;
            int pos = offs_l[b] + atomicAdd(&lcur[b], 1);
            packed[pos] = ((unsigned)(r & (BROWS - 1)) << 17) | (unsigned)c;
        }
    }
}

// ---------- K6: per-bucket LDS counting-sort + reg-accum SpMM + log_softmax ----------
__global__ __launch_bounds__(512) void LINK_62689342652831_spmm_kernel(
    const unsigned int* __restrict__ packed, const int* __restrict__ bstart,
    const unsigned short* __restrict__ Wtb, const float* __restrict__ bias,
    float* __restrict__ out) {
    __shared__ unsigned int sh[2 * STAGECAP + BROWS + (BROWS + 1) + BROWS];
    unsigned int* stage = sh;
    unsigned int* sorted = sh + STAGECAP;
    int* rhist = (int*)(sh + 2 * STAGECAP);
    int* rstart = rhist + BROWS;           // 129 entries
    int* rcur = rstart + BROWS + 1;

    int lane = threadIdx.x & 63;
    int wid = threadIdx.x >> 6;  // 0..7
    int b = blockIdx.x;
    int s = bstart[b], e = bstart[b + 1];
    int n = e - s;
    float bsv = bias[lane];

    if (n <= STAGECAP) {
        for (int i = threadIdx.x; i < n; i += 512) stage[i] = packed[s + i];
        if (threadIdx.x < BROWS) rhist[threadIdx.x] = 0;
        __syncthreads();
        for (int i = threadIdx.x; i < n; i += 512) atomicAdd(&rhist[stage[i] >> 17], 1);
        __syncthreads();
        if (wid == 0) {
            int c0 = rhist[lane], c1 = rhist[lane + 64];
            int x0 = c0, x1 = c1;
            for (int off = 1; off < 64; off <<= 1) {
                int y0 = __shfl_up(x0, off, 64);
                int y1 = __shfl_up(x1, off, 64);
                if (lane >= off) { x0 += y0; x1 += y1; }
            }
            int t0 = __shfl(x0, 63, 64);  // sum of first 64
            rstart[lane] = x0 - c0;
            rstart[lane + 64] = x1 - c1 + t0;
            rcur[lane] = x0 - c0;
            rcur[lane + 64] = x1 - c1 + t0;
            if (lane == 63) rstart[128] = x1 + t0;
        }
        __syncthreads();
        for (int i = threadIdx.x; i < n; i += 512) {
            unsigned int u = stage[i];
            int pos = atomicAdd(&rcur[u >> 17], 1);
            sorted[pos] = u;
        }
        __syncthreads();

        for (int r = wid; r < BROWS; r += 8) {
            int gr = b * BROWS + r;
            if (gr >= NUM_NODES) continue;
            int s0 = rstart[r], e0 = rstart[r + 1];
            float acc = 0.0f;
            int i = s0;
            for (; i + 8 <= e0; i += 8) {
                unsigned int u0 = sorted[i], u1 = sorted[i + 1], u2 = sorted[i + 2],
                             u3 = sorted[i + 3], u4 = sorted[i + 4], u5 = sorted[i + 5],
                             u6 = sorted[i + 6], u7 = sorted[i + 7];
                float v0 = __uint_as_float((unsigned int)Wtb[(size_t)(u0 & 0x1FFFF) * OUT_CH + lane] << 16);
                float v1 = __uint_as_float((unsigned int)Wtb[(size_t)(u1 & 0x1FFFF) * OUT_CH + lane] << 16);
                float v2 = __uint_as_float((unsigned int)Wtb[(size_t)(u2 & 0x1FFFF) * OUT_CH + lane] << 16);
                float v3 = __uint_as_float((unsigned int)Wtb[(size_t)(u3 & 0x1FFFF) * OUT_CH + lane] << 16);
                float v4 = __uint_as_float((unsigned int)Wtb[(size_t)(u4 & 0x1FFFF) * OUT_CH + lane] << 16);
                float v5 = __uint_as_float((unsigned int)Wtb[(size_t)(u5 & 0x1FFFF) * OUT_CH + lane] << 16);
                float v6 = __uint_as_float((unsigned int)Wtb[(size_t)(u6 & 0x1FFFF) * OUT_CH + lane] << 16);
                float v7 = __uint_as_float((unsigned int)Wtb[(size_t)(u7 & 0x1FFFF) * OUT_CH + lane] << 16);
                acc += ((v0 + v1) + (v2 + v3)) + ((v4 + v5) + (v6 + v7));
            }
            for (; i < e0; ++i)
                acc += __uint_as_float((unsigned int)Wtb[(size_t)(sorted[i] & 0x1FFFF) * OUT_CH + lane] << 16);

            float x = acc + bsv;
            float m = x;
            for (int off = 32; off > 0; off >>= 1) m = fmaxf(m, __shfl_xor(m, off, 64));
            float ex = expf(x - m);
            float ssum = ex;
            for (int off = 32; off > 0; off >>= 1) ssum += __shfl_xor(ssum, off, 64);
            out[(size_t)gr * OUT_CH + lane] = x - m - logf(ssum);
        }
    } else {
        // overflow fallback: LDS-atomic accumulate (correct, slow, ~never taken)
        float* acc = (float*)sh;  // 128*64 floats = 32 KB fits in stage+sorted
        for (int i = threadIdx.x; i < BROWS * OUT_CH; i += 512) acc[i] = 0.0f;
        __syncthreads();
        for (int i = s + wid; i < e; i += 8) {
            unsigned int u = packed[i];
            float v = __uint_as_float((unsigned int)Wtb[(size_t)(u & 0x1FFFF) * OUT_CH + lane] << 16);
            atomicAdd(&acc[(u >> 17) * OUT_CH + lane], v);
        }
        __syncthreads();
        for (int r = wid; r < BROWS; r += 8) {
            int gr = b * BROWS + r;
            if (gr >= NUM_NODES) continue;
            float x = acc[r * OUT_CH + lane] + bsv;
            float m = x;
            for (int off = 32; off > 0; off >>= 1) m = fmaxf(m, __shfl_xor(m, off, 64));
            float ex = expf(x - m);
            float ssum = ex;
            for (int off = 32; off > 0; off >>= 1) ssum += __shfl_xor(ssum, off, 64);
            out[(size_t)gr * OUT_CH + lane] = x - m - logf(ssum);
        }
    }
}

// ---------- fallback (round-1 path, direct W) ----------
__global__ void LINK_62689342652831_minf_kernel(const int* __restrict__ rows, int n,
                                                int* __restrict__ minp) {
    int tid = blockIdx.x * blockDim.x + threadIdx.x;
    int stride = gridDim.x * blockDim.x;
    int m = INT_MAX;
    for (int i = tid; i < n; i += stride) m = min(m, rows[i]);
    for (int off = 32; off > 0; off >>= 1) m = min(m, __shfl_xor(m, off, 64));
    if ((threadIdx.x & 63) == 0) atomicMin(minp, m);
}

__global__ void LINK_62689342652831_scatter_kernel(const int* __restrict__ rows,
                                                   const int* __restrict__ cols,
                                                   const float* __restrict__ W,
                                                   const int* __restrict__ minp,
                                                   float* __restrict__ out) {
    int lane = threadIdx.x & 63;
    int gw = (blockIdx.x * blockDim.x + threadIdx.x) >> 6;
    int nw = (gridDim.x * blockDim.x) >> 6;
    int minv = *minp;
    for (int e = gw; e < NUM_EDGES; e += nw) {
        int r = rows[e] - minv;
        int c = cols[e];
        float v = W[(size_t)lane * NUM_NODES + c];
        unsafeAtomicAdd(&out[(size_t)r * 64 + lane], v);
    }
}

__global__ void LINK_62689342652831_logsoftmax_kernel(float* __restrict__ out,
                                                      const float* __restrict__ bias) {
    int lane = threadIdx.x & 63;
    int gw = (blockIdx.x * blockDim.x + threadIdx.x) >> 6;
    int nw = (gridDim.x * blockDim.x) >> 6;
    float b = bias[lane];
    for (int r = gw; r < NUM_NODES; r += nw) {
        float x = out[(size_t)r * 64 + lane] + b;
        float m = x;
        for (int off = 32; off > 0; off >>= 1) m = fmaxf(m, __shfl_xor(m, off, 64));
        float e = expf(x - m);
        float s = e;
        for (int off = 32; off > 0; off >>= 1) s += __shfl_xor(s, off, 64);
        out[(size_t)r * 64 + lane] = x - m - logf(s);
    }
}

extern "C" void kernel_launch(void* const* d_in, const int* in_sizes, int n_in,
                              void* d_out, int out_size, void* d_ws, size_t ws_size,
                              hipStream_t stream) {
    const int* edges = (const int*)d_in[0];
    const int* rows = edges;
    const int* cols = edges + NUM_EDGES;
    const float* W = (const float*)d_in[1];
    const float* bias = (const float*)d_in[2];
    float* out = (float*)d_out;

    // workspace layout
    char* ws = (char*)d_ws;
    const size_t OFF_MIN = 0;                                  // 4 B
    const size_t OFF_BSTART = 256;                             // (NBUCK+1)*4 = 3132 B
    const size_t OFF_TOT = 4096;                               // NBUCK*4 B
    const size_t OFF_H2D = 8192;                               // 256*782*4 = 800768 B
    const size_t OFF_PACKED = 1024 * 1024;                     // 12.8 MB
    const size_t OFF_WTB = OFF_PACKED + (size_t)NUM_EDGES * 4; // 12.8 MB
    const size_t need = OFF_WTB + (size_t)NUM_NODES * OUT_CH * 2;

    int* minp = (int*)(ws + OFF_MIN);
    int* bstart = (int*)(ws + OFF_BSTART);
    int* totals = (int*)(ws + OFF_TOT);
    int* hist2d = (int*)(ws + OFF_H2D);
    unsigned int* packed = (unsigned int*)(ws + OFF_PACKED);
    unsigned short* Wtb = (unsigned short*)(ws + OFF_WTB);

    hipMemsetAsync(minp, 0x7f, sizeof(int), stream);

    if (ws_size >= need) {
        LINK_62689342652831_min_kernel<<<PGRID, 256, 0, stream>>>(rows, minp);
        LINK_62689342652831_transpose_kernel<<<(NUM_NODES + 63) / 64, 256, 0, stream>>>(W, Wtb);
        LINK_62689342652831_hist2d_kernel<<<NPBLK, 512, 0, stream>>>(rows, minp, hist2d);
        LINK_62689342652831_colscan_kernel<<<(NBUCK + 7) / 8, 512, 0, stream>>>(hist2d, totals);
        LINK_62689342652831_bscan_kernel<<<1, 1024, 0, stream>>>(totals, bstart);
        LINK_62689342652831_part_kernel<<<NPBLK, 512, 0, stream>>>(rows, cols, minp, hist2d,
                                                                   bstart, packed);
        LINK_62689342652831_spmm_kernel<<<NBUCK, 512, 0, stream>>>(packed, bstart, Wtb,
                                                                   bias, out);
    } else {
        LINK_62689342652831_minf_kernel<<<2048, 256, 0, stream>>>(rows, NUM_EDGES, minp);
        hipMemsetAsync(d_out, 0, (size_t)out_size * sizeof(float), stream);
        LINK_62689342652831_scatter_kernel<<<2048, 256, 0, stream>>>(rows, cols, W, minp, out);
        LINK_62689342652831_logsoftmax_kernel<<<4096, 256, 0, stream>>>(out, bias);
    }
}

// Round 7
// 185.210 us; speedup vs baseline: 9.4724x; 1.7493x over previous
//
#include <hip/hip_runtime.h>
#include <hip/hip_bf16.h>
#include <limits.h>

#define NUM_NODES 100000
#define OUT_CH 64
#define NUM_EDGES 3200000
#define BROWS 128                    // rows per bucket
#define NBUCK 782                    // ceil(100000/128); 782*128 = 100096
#define NPBLK 256                    // partition blocks
#define EPB (NUM_EDGES / NPBLK)      // 12500 edges per partition block
#define I4PB (EPB / 4)               // 3125 int4 per partition block
#define STAGECAP 6144                // LDS staging cap (avg 4092, sigma~64)

// ---------- K1: min of edge_index[0] — two-stage (1 atomic per block) ----------
__global__ __launch_bounds__(256) void LINK_62689342652831_min_kernel(
    const int* __restrict__ rows, int* __restrict__ minp) {
    int tid = blockIdx.x * 256 + threadIdx.x;
    int stride = gridDim.x * 256;
    const int4* r4 = (const int4*)rows;
    int m = INT_MAX;
    for (int i = tid; i < NUM_EDGES / 4; i += stride) {
        int4 v = r4[i];
        m = min(m, min(min(v.x, v.y), min(v.z, v.w)));
    }
    for (int off = 32; off > 0; off >>= 1) m = min(m, __shfl_xor(m, off, 64));
    __shared__ int sm[4];
    if ((threadIdx.x & 63) == 0) sm[threadIdx.x >> 6] = m;
    __syncthreads();
    if (threadIdx.x == 0) {
        int mm = min(min(sm[0], sm[1]), min(sm[2], sm[3]));
        atomicMin(minp, mm);
    }
}

// ---------- K2: transpose W [64][N] -> Wtb [N][64] bf16 ----------
__global__ void LINK_62689342652831_transpose_kernel(const float* __restrict__ W,
                                                     unsigned short* __restrict__ Wtb) {
    __shared__ float tile[64][65];
    int n0 = blockIdx.x * 64;
    int tx = threadIdx.x & 63;
    int ty = threadIdx.x >> 6;
    for (int c = ty; c < 64; c += 4) {
        int n = n0 + tx;
        tile[c][tx] = (n < NUM_NODES) ? W[(size_t)c * NUM_NODES + n] : 0.0f;
    }
    __syncthreads();
    for (int i = ty; i < 64; i += 4) {
        int n = n0 + i;
        if (n < NUM_NODES) {
            __hip_bfloat16 bv = __float2bfloat16(tile[tx][i]);
            Wtb[(size_t)n * OUT_CH + tx] = *(unsigned short*)&bv;
        }
    }
}

// ---------- K3: per-block bucket histogram -> hist2d[blk][bucket] ----------
__global__ __launch_bounds__(512) void LINK_62689342652831_hist2d_kernel(
    const int* __restrict__ rows, const int* __restrict__ minp,
    int* __restrict__ hist2d) {
    __shared__ int h[NBUCK];
    for (int i = threadIdx.x; i < NBUCK; i += 512) h[i] = 0;
    __syncthreads();
    int minv = *minp;
    int blk = blockIdx.x;
    const int4* r4 = (const int4*)rows;
    for (int i = threadIdx.x; i < I4PB; i += 512) {
        int4 v = r4[blk * I4PB + i];
        atomicAdd(&h[(unsigned)(v.x - minv) >> 7], 1);
        atomicAdd(&h[(unsigned)(v.y - minv) >> 7], 1);
        atomicAdd(&h[(unsigned)(v.z - minv) >> 7], 1);
        atomicAdd(&h[(unsigned)(v.w - minv) >> 7], 1);
    }
    __syncthreads();
    for (int i = threadIdx.x; i < NBUCK; i += 512) hist2d[blk * NBUCK + i] = h[i];
}

// ---------- K4a: per-bucket prefix over the 256 blocks (in-place) ----------
__global__ __launch_bounds__(512) void LINK_62689342652831_colscan_kernel(
    int* __restrict__ hist2d, int* __restrict__ totals) {
    int lane = threadIdx.x & 63;
    int wid = threadIdx.x >> 6;
    int b = blockIdx.x * 8 + wid;
    if (b >= NBUCK) return;
    int carry = 0;
    for (int rnd = 0; rnd < NPBLK / 64; ++rnd) {
        int blk = rnd * 64 + lane;
        int v = hist2d[blk * NBUCK + b];
        int x = v;
        for (int off = 1; off < 64; off <<= 1) {
            int y = __shfl_up(x, off, 64);
            if (lane >= off) x += y;
        }
        hist2d[blk * NBUCK + b] = x - v + carry;  // exclusive + carry
        carry += __shfl(x, 63, 64);
    }
    if (lane == 0) totals[b] = carry;
}

// ---------- K4b: scan bucket totals -> bstart[0..NBUCK] ----------
__global__ __launch_bounds__(1024) void LINK_62689342652831_bscan_kernel(
    const int* __restrict__ totals, int* __restrict__ bstart) {
    __shared__ int ss[1024];
    int t = threadIdx.x;
    int v = (t < NBUCK) ? totals[t] : 0;
    ss[t] = v;
    __syncthreads();
    for (int off = 1; off < 1024; off <<= 1) {
        int x = (t >= off) ? ss[t - off] : 0;
        __syncthreads();
        ss[t] += x;
        __syncthreads();
    }
    if (t < NBUCK) bstart[t] = ss[t] - v;
    if (t == NBUCK - 1) bstart[NBUCK] = ss[t];
}

// ---------- K5: partition edges into bucket regions (no global atomics) ----------
__global__ __launch_bounds__(512) void LINK_62689342652831_part_kernel(
    const int* __restrict__ rows, const int* __restrict__ cols,
    const int* __restrict__ minp, const int* __restrict__ hist2d,
    const int* __restrict__ bstart, unsigned int* __restrict__ packed) {
    __shared__ int offs_l[NBUCK];
    __shared__ int lcur[NBUCK];
    int blk = blockIdx.x;
    for (int i = threadIdx.x; i < NBUCK; i += 512) {
        offs_l[i] = bstart[i] + hist2d[blk * NBUCK + i];
        lcur[i] = 0;
    }
    __syncthreads();
    int minv = *minp;
    const int4* r4 = (const int4*)rows;
    const int4* c4 = (const int4*)cols;
    for (int i = threadIdx.x; i < I4PB; i += 512) {
        int4 rv = r4[blk * I4PB + i];
        int4 cv = c4[blk * I4PB + i];
#pragma unroll
        for (int k = 0; k < 4; ++k) {
            int r = ((k == 0) ? rv.x : (k == 1) ? rv.y : (k == 2) ? rv.z : rv.w) - minv;
            int c = (k == 0) ? cv.x : (k == 1) ? cv.y : (k == 2) ? cv.z : cv.w;
            int b = (unsigned)r >> 7;
            int pos = offs_l[b] + atomicAdd(&lcur[b], 1);
            packed[pos] = ((unsigned)(r & (BROWS - 1)) << 17) | (unsigned)c;
        }
    }
}

// ---------- K6: per-bucket LDS counting-sort + reg-accum SpMM + log_softmax ----------
__global__ __launch_bounds__(512) void LINK_62689342652831_spmm_kernel(
    const unsigned int* __restrict__ packed, const int* __restrict__ bstart,
    const unsigned short* __restrict__ Wtb, const float* __restrict__ bias,
    float* __restrict__ out) {
    __shared__ unsigned int sh[2 * STAGECAP + BROWS + (BROWS + 1) + BROWS];
    unsigned int* stage = sh;
    unsigned int* sorted = sh + STAGECAP;
    int* rhist = (int*)(sh + 2 * STAGECAP);
    int* rstart = rhist + BROWS;           // 129 entries
    int* rcur = rstart + BROWS + 1;

    int lane = threadIdx.x & 63;
    int wid = threadIdx.x >> 6;  // 0..7
    int b = blockIdx.x;
    int s = bstart[b], e = bstart[b + 1];
    int n = e - s;
    float bsv = bias[lane];

    if (n <= STAGECAP) {
        for (int i = threadIdx.x; i < n; i += 512) stage[i] = packed[s + i];
        if (threadIdx.x < BROWS) rhist[threadIdx.x] = 0;
        __syncthreads();
        for (int i = threadIdx.x; i < n; i += 512) atomicAdd(&rhist[stage[i] >> 17], 1);
        __syncthreads();
        if (wid == 0) {
            int c0 = rhist[lane], c1 = rhist[lane + 64];
            int x0 = c0, x1 = c1;
            for (int off = 1; off < 64; off <<= 1) {
                int y0 = __shfl_up(x0, off, 64);
                int y1 = __shfl_up(x1, off, 64);
                if (lane >= off) { x0 += y0; x1 += y1; }
            }
            int t0 = __shfl(x0, 63, 64);  // sum of first 64
            rstart[lane] = x0 - c0;
            rstart[lane + 64] = x1 - c1 + t0;
            rcur[lane] = x0 - c0;
            rcur[lane + 64] = x1 - c1 + t0;
            if (lane == 63) rstart[128] = x1 + t0;
        }
        __syncthreads();
        for (int i = threadIdx.x; i < n; i += 512) {
            unsigned int u = stage[i];
            int pos = atomicAdd(&rcur[u >> 17], 1);
            sorted[pos] = u;
        }
        __syncthreads();

        for (int r = wid; r < BROWS; r += 8) {
            int gr = b * BROWS + r;
            if (gr >= NUM_NODES) continue;
            int s0 = rstart[r], e0 = rstart[r + 1];
            float acc = 0.0f;
            int i = s0;
            for (; i + 8 <= e0; i += 8) {
                unsigned int u0 = sorted[i], u1 = sorted[i + 1], u2 = sorted[i + 2],
                             u3 = sorted[i + 3], u4 = sorted[i + 4], u5 = sorted[i + 5],
                             u6 = sorted[i + 6], u7 = sorted[i + 7];
                float v0 = __uint_as_float((unsigned int)Wtb[(size_t)(u0 & 0x1FFFF) * OUT_CH + lane] << 16);
                float v1 = __uint_as_float((unsigned int)Wtb[(size_t)(u1 & 0x1FFFF) * OUT_CH + lane] << 16);
                float v2 = __uint_as_float((unsigned int)Wtb[(size_t)(u2 & 0x1FFFF) * OUT_CH + lane] << 16);
                float v3 = __uint_as_float((unsigned int)Wtb[(size_t)(u3 & 0x1FFFF) * OUT_CH + lane] << 16);
                float v4 = __uint_as_float((unsigned int)Wtb[(size_t)(u4 & 0x1FFFF) * OUT_CH + lane] << 16);
                float v5 = __uint_as_float((unsigned int)Wtb[(size_t)(u5 & 0x1FFFF) * OUT_CH + lane] << 16);
                float v6 = __uint_as_float((unsigned int)Wtb[(size_t)(u6 & 0x1FFFF) * OUT_CH + lane] << 16);
                float v7 = __uint_as_float((unsigned int)Wtb[(size_t)(u7 & 0x1FFFF) * OUT_CH + lane] << 16);
                acc += ((v0 + v1) + (v2 + v3)) + ((v4 + v5) + (v6 + v7));
            }
            for (; i < e0; ++i)
                acc += __uint_as_float((unsigned int)Wtb[(size_t)(sorted[i] & 0x1FFFF) * OUT_CH + lane] << 16);

            float x = acc + bsv;
            float m = x;
            for (int off = 32; off > 0; off >>= 1) m = fmaxf(m, __shfl_xor(m, off, 64));
            float ex = expf(x - m);
            float ssum = ex;
            for (int off = 32; off > 0; off >>= 1) ssum += __shfl_xor(ssum, off, 64);
            out[(size_t)gr * OUT_CH + lane] = x - m - logf(ssum);
        }
    } else {
        // overflow fallback: LDS-atomic accumulate (correct, slow, ~never taken)
        float* acc = (float*)sh;  // 128*64 floats = 32 KB fits in stage+sorted
        for (int i = threadIdx.x; i < BROWS * OUT_CH; i += 512) acc[i] = 0.0f;
        __syncthreads();
        for (int i = s + wid; i < e; i += 8) {
            unsigned int u = packed[i];
            float v = __uint_as_float((unsigned int)Wtb[(size_t)(u & 0x1FFFF) * OUT_CH + lane] << 16);
            atomicAdd(&acc[(u >> 17) * OUT_CH + lane], v);
        }
        __syncthreads();
        for (int r = wid; r < BROWS; r += 8) {
            int gr = b * BROWS + r;
            if (gr >= NUM_NODES) continue;
            float x = acc[r * OUT_CH + lane] + bsv;
            float m = x;
            for (int off = 32; off > 0; off >>= 1) m = fmaxf(m, __shfl_xor(m, off, 64));
            float ex = expf(x - m);
            float ssum = ex;
            for (int off = 32; off > 0; off >>= 1) ssum += __shfl_xor(ssum, off, 64);
            out[(size_t)gr * OUT_CH + lane] = x - m - logf(ssum);
        }
    }
}

// ---------- fallback (round-1 path, direct W) ----------
__global__ void LINK_62689342652831_minf_kernel(const int* __restrict__ rows, int n,
                                                int* __restrict__ minp) {
    int tid = blockIdx.x * blockDim.x + threadIdx.x;
    int stride = gridDim.x * blockDim.x;
    int m = INT_MAX;
    for (int i = tid; i < n; i += stride) m = min(m, rows[i]);
    for (int off = 32; off > 0; off >>= 1) m = min(m, __shfl_xor(m, off, 64));
    if ((threadIdx.x & 63) == 0) atomicMin(minp, m);
}

__global__ void LINK_62689342652831_scatter_kernel(const int* __restrict__ rows,
                                                   const int* __restrict__ cols,
                                                   const float* __restrict__ W,
                                                   const int* __restrict__ minp,
                                                   float* __restrict__ out) {
    int lane = threadIdx.x & 63;
    int gw = (blockIdx.x * blockDim.x + threadIdx.x) >> 6;
    int nw = (gridDim.x * blockDim.x) >> 6;
    int minv = *minp;
    for (int e = gw; e < NUM_EDGES; e += nw) {
        int r = rows[e] - minv;
        int c = cols[e];
        float v = W[(size_t)lane * NUM_NODES + c];
        unsafeAtomicAdd(&out[(size_t)r * 64 + lane], v);
    }
}

__global__ void LINK_62689342652831_logsoftmax_kernel(float* __restrict__ out,
                                                      const float* __restrict__ bias) {
    int lane = threadIdx.x & 63;
    int gw = (blockIdx.x * blockDim.x + threadIdx.x) >> 6;
    int nw = (gridDim.x * blockDim.x) >> 6;
    float b = bias[lane];
    for (int r = gw; r < NUM_NODES; r += nw) {
        float x = out[(size_t)r * 64 + lane] + b;
        float m = x;
        for (int off = 32; off > 0; off >>= 1) m = fmaxf(m, __shfl_xor(m, off, 64));
        float e = expf(x - m);
        float s = e;
        for (int off = 32; off > 0; off >>= 1) s += __shfl_xor(s, off, 64);
        out[(size_t)r * 64 + lane] = x - m - logf(s);
    }
}

extern "C" void kernel_launch(void* const* d_in, const int* in_sizes, int n_in,
                              void* d_out, int out_size, void* d_ws, size_t ws_size,
                              hipStream_t stream) {
    const int* edges = (const int*)d_in[0];
    const int* rows = edges;
    const int* cols = edges + NUM_EDGES;
    const float* W = (const float*)d_in[1];
    const float* bias = (const float*)d_in[2];
    float* out = (float*)d_out;

    // workspace layout
    char* ws = (char*)d_ws;
    const size_t OFF_MIN = 0;                                  // 4 B
    const size_t OFF_BSTART = 256;                             // (NBUCK+1)*4 = 3132 B
    const size_t OFF_TOT = 4096;                               // NBUCK*4 B
    const size_t OFF_H2D = 8192;                               // 256*782*4 = 800768 B
    const size_t OFF_PACKED = 1024 * 1024;                     // 12.8 MB
    const size_t OFF_WTB = OFF_PACKED + (size_t)NUM_EDGES * 4; // 12.8 MB
    const size_t need = OFF_WTB + (size_t)NUM_NODES * OUT_CH * 2;

    int* minp = (int*)(ws + OFF_MIN);
    int* bstart = (int*)(ws + OFF_BSTART);
    int* totals = (int*)(ws + OFF_TOT);
    int* hist2d = (int*)(ws + OFF_H2D);
    unsigned int* packed = (unsigned int*)(ws + OFF_PACKED);
    unsigned short* Wtb = (unsigned short*)(ws + OFF_WTB);

    hipMemsetAsync(minp, 0x7f, sizeof(int), stream);

    if (ws_size >= need) {
        LINK_62689342652831_min_kernel<<<256, 256, 0, stream>>>(rows, minp);
        LINK_62689342652831_transpose_kernel<<<(NUM_NODES + 63) / 64, 256, 0, stream>>>(W, Wtb);
        LINK_62689342652831_hist2d_kernel<<<NPBLK, 512, 0, stream>>>(rows, minp, hist2d);
        LINK_62689342652831_colscan_kernel<<<(NBUCK + 7) / 8, 512, 0, stream>>>(hist2d, totals);
        LINK_62689342652831_bscan_kernel<<<1, 1024, 0, stream>>>(totals, bstart);
        LINK_62689342652831_part_kernel<<<NPBLK, 512, 0, stream>>>(rows, cols, minp, hist2d,
                                                                   bstart, packed);
        LINK_62689342652831_spmm_kernel<<<NBUCK, 512, 0, stream>>>(packed, bstart, Wtb,
                                                                   bias, out);
    } else {
        LINK_62689342652831_minf_kernel<<<2048, 256, 0, stream>>>(rows, NUM_EDGES, minp);
        hipMemsetAsync(d_out, 0, (size_t)out_size * sizeof(float), stream);
        LINK_62689342652831_scatter_kernel<<<2048, 256, 0, stream>>>(rows, cols, W, minp, out);
        LINK_62689342652831_logsoftmax_kernel<<<4096, 256, 0, stream>>>(out, bias);
    }
}

// Round 8
// 132.627 us; speedup vs baseline: 13.2280x; 1.3965x over previous
//
#include <hip/hip_runtime.h>
#include <hip/hip_bf16.h>
#include <limits.h>

#define NUM_NODES 100000
#define OUT_CH 64
#define NUM_EDGES 3200000
#define BROWS 128                    // rows per bucket
#define NBUCK 782                    // ceil(100000/128); 782*128 = 100096
#define NPBLK 256                    // partition blocks
#define EPB (NUM_EDGES / NPBLK)      // 12500 edges per partition block
#define I4PB (EPB / 4)               // 3125 int4 per partition block
#define STAGECAP 6144                // per-bucket LDS sort cap (avg 4092)

// ---------- K1: min of edge_index[0] — two-stage (1 atomic per block) ----------
__global__ __launch_bounds__(256) void LINK_62689342652831_min_kernel(
    const int* __restrict__ rows, int* __restrict__ minp) {
    int tid = blockIdx.x * 256 + threadIdx.x;
    int stride = gridDim.x * 256;
    const int4* r4 = (const int4*)rows;
    int m = INT_MAX;
    for (int i = tid; i < NUM_EDGES / 4; i += stride) {
        int4 v = r4[i];
        m = min(m, min(min(v.x, v.y), min(v.z, v.w)));
    }
    for (int off = 32; off > 0; off >>= 1) m = min(m, __shfl_xor(m, off, 64));
    __shared__ int sm[4];
    if ((threadIdx.x & 63) == 0) sm[threadIdx.x >> 6] = m;
    __syncthreads();
    if (threadIdx.x == 0) {
        int mm = min(min(sm[0], sm[1]), min(sm[2], sm[3]));
        atomicMin(minp, mm);
    }
}

// ---------- K2: transpose W [64][N] -> Wtb [N][64] bf16 ----------
__global__ void LINK_62689342652831_transpose_kernel(const float* __restrict__ W,
                                                     unsigned short* __restrict__ Wtb) {
    __shared__ float tile[64][65];
    int n0 = blockIdx.x * 64;
    int tx = threadIdx.x & 63;
    int ty = threadIdx.x >> 6;
    for (int c = ty; c < 64; c += 4) {
        int n = n0 + tx;
        tile[c][tx] = (n < NUM_NODES) ? W[(size_t)c * NUM_NODES + n] : 0.0f;
    }
    __syncthreads();
    for (int i = ty; i < 64; i += 4) {
        int n = n0 + i;
        if (n < NUM_NODES) {
            __hip_bfloat16 bv = __float2bfloat16(tile[tx][i]);
            Wtb[(size_t)n * OUT_CH + tx] = *(unsigned short*)&bv;
        }
    }
}

// ---------- K3: per-block bucket histogram -> hist2d[blk][bucket] ----------
__global__ __launch_bounds__(512) void LINK_62689342652831_hist2d_kernel(
    const int* __restrict__ rows, const int* __restrict__ minp,
    int* __restrict__ hist2d) {
    __shared__ int h[NBUCK];
    for (int i = threadIdx.x; i < NBUCK; i += 512) h[i] = 0;
    __syncthreads();
    int minv = *minp;
    int blk = blockIdx.x;
    const int4* r4 = (const int4*)rows;
    for (int i = threadIdx.x; i < I4PB; i += 512) {
        int4 v = r4[blk * I4PB + i];
        atomicAdd(&h[(unsigned)(v.x - minv) >> 7], 1);
        atomicAdd(&h[(unsigned)(v.y - minv) >> 7], 1);
        atomicAdd(&h[(unsigned)(v.z - minv) >> 7], 1);
        atomicAdd(&h[(unsigned)(v.w - minv) >> 7], 1);
    }
    __syncthreads();
    for (int i = threadIdx.x; i < NBUCK; i += 512) hist2d[blk * NBUCK + i] = h[i];
}

// ---------- K4a: per-bucket prefix over the 256 blocks (in-place) ----------
__global__ __launch_bounds__(512) void LINK_62689342652831_colscan_kernel(
    int* __restrict__ hist2d, int* __restrict__ totals) {
    int lane = threadIdx.x & 63;
    int wid = threadIdx.x >> 6;
    int b = blockIdx.x * 8 + wid;
    if (b >= NBUCK) return;
    int carry = 0;
    for (int rnd = 0; rnd < NPBLK / 64; ++rnd) {
        int blk = rnd * 64 + lane;
        int v = hist2d[blk * NBUCK + b];
        int x = v;
        for (int off = 1; off < 64; off <<= 1) {
            int y = __shfl_up(x, off, 64);
            if (lane >= off) x += y;
        }
        hist2d[blk * NBUCK + b] = x - v + carry;  // exclusive + carry
        carry += __shfl(x, 63, 64);
    }
    if (lane == 0) totals[b] = carry;
}

// ---------- K4b: scan bucket totals -> bstart[0..NBUCK] ----------
__global__ __launch_bounds__(1024) void LINK_62689342652831_bscan_kernel(
    const int* __restrict__ totals, int* __restrict__ bstart) {
    __shared__ int ss[1024];
    int t = threadIdx.x;
    int v = (t < NBUCK) ? totals[t] : 0;
    ss[t] = v;
    __syncthreads();
    for (int off = 1; off < 1024; off <<= 1) {
        int x = (t >= off) ? ss[t - off] : 0;
        __syncthreads();
        ss[t] += x;
        __syncthreads();
    }
    if (t < NBUCK) bstart[t] = ss[t] - v;
    if (t == NBUCK - 1) bstart[NBUCK] = ss[t];
}

// ---------- K5: partition edges into bucket regions (no global atomics) ----------
__global__ __launch_bounds__(512) void LINK_62689342652831_part_kernel(
    const int* __restrict__ rows, const int* __restrict__ cols,
    const int* __restrict__ minp, const int* __restrict__ hist2d,
    const int* __restrict__ bstart, unsigned int* __restrict__ packed) {
    __shared__ int offs_l[NBUCK];
    __shared__ int lcur[NBUCK];
    int blk = blockIdx.x;
    for (int i = threadIdx.x; i < NBUCK; i += 512) {
        offs_l[i] = bstart[i] + hist2d[blk * NBUCK + i];
        lcur[i] = 0;
    }
    __syncthreads();
    int minv = *minp;
    const int4* r4 = (const int4*)rows;
    const int4* c4 = (const int4*)cols;
    for (int i = threadIdx.x; i < I4PB; i += 512) {
        int4 rv = r4[blk * I4PB + i];
        int4 cv = c4[blk * I4PB + i];
#pragma unroll
        for (int k = 0; k < 4; ++k) {
            int r = ((k == 0) ? rv.x : (k == 1) ? rv.y : (k == 2) ? rv.z : rv.w) - minv;
            int c = (k == 0) ? cv.x : (k == 1) ? cv.y : (k == 2) ? cv.z : cv.w;
            int b = (unsigned)r >> 7;
            int pos = offs_l[b] + atomicAdd(&lcur[b], 1);
            packed[pos] = ((unsigned)(r & (BROWS - 1)) << 17) | (unsigned)c;
        }
    }
}

// ---------- K6: per-bucket counting-sort + 4ch/lane reg-accum SpMM + log_softmax ----------
__global__ __launch_bounds__(512) void LINK_62689342652831_spmm_kernel(
    const unsigned int* __restrict__ packed, const int* __restrict__ bstart,
    const unsigned short* __restrict__ Wtb, const float* __restrict__ bias,
    float* __restrict__ out) {
    __shared__ unsigned int sh[8192];        // sorted (<=6144) OR acc (8192 floats, fallback)
    __shared__ int rhist[BROWS];
    __shared__ int rstart[BROWS + 1];
    __shared__ int rcur[BROWS];
    unsigned int* sorted = sh;

    int lane = threadIdx.x & 63;
    int wid = threadIdx.x >> 6;  // 0..7
    int b = blockIdx.x;
    int s = bstart[b], e = bstart[b + 1];
    int n = e - s;

    if (n <= STAGECAP) {
        if (threadIdx.x < BROWS) rhist[threadIdx.x] = 0;
        __syncthreads();
        for (int i = threadIdx.x; i < n; i += 512)
            atomicAdd(&rhist[packed[s + i] >> 17], 1);
        __syncthreads();
        if (wid == 0) {
            int c0 = rhist[lane], c1 = rhist[lane + 64];
            int x0 = c0, x1 = c1;
            for (int off = 1; off < 64; off <<= 1) {
                int y0 = __shfl_up(x0, off, 64);
                int y1 = __shfl_up(x1, off, 64);
                if (lane >= off) { x0 += y0; x1 += y1; }
            }
            int t0 = __shfl(x0, 63, 64);
            rstart[lane] = x0 - c0;
            rstart[lane + 64] = x1 - c1 + t0;
            rcur[lane] = x0 - c0;
            rcur[lane + 64] = x1 - c1 + t0;
            if (lane == 63) rstart[128] = x1 + t0;
        }
        __syncthreads();
        for (int i = threadIdx.x; i < n; i += 512) {
            unsigned int u = packed[s + i];
            int pos = atomicAdd(&rcur[u >> 17], 1);
            sorted[pos] = u;
        }
        __syncthreads();

        // gather: 16 lanes per edge (uint2 = 4 bf16 channels/lane), 4 edges per wave
        const uint2* Wt2 = (const uint2*)Wtb;  // row stride = 16 uint2
        int q = lane >> 4;    // quarter 0..3
        int ql = lane & 15;   // channels 4ql .. 4ql+3
        float b0 = bias[4 * ql], b1 = bias[4 * ql + 1],
              b2 = bias[4 * ql + 2], b3 = bias[4 * ql + 3];

        for (int r = wid; r < BROWS; r += 8) {
            int gr = b * BROWS + r;
            if (gr >= NUM_NODES) continue;
            int s0 = rstart[r], e0 = rstart[r + 1];
            float a0 = 0, a1 = 0, a2 = 0, a3 = 0;
            int i = s0 + q;
            for (; i + 4 < e0; i += 8) {  // 2 independent edges in flight
                unsigned int ua = sorted[i], ub = sorted[i + 4];
                uint2 wa = Wt2[(size_t)(ua & 0x1FFFF) * 16 + ql];
                uint2 wb = Wt2[(size_t)(ub & 0x1FFFF) * 16 + ql];
                a0 += __uint_as_float(wa.x << 16);
                a1 += __uint_as_float(wa.x & 0xFFFF0000u);
                a2 += __uint_as_float(wa.y << 16);
                a3 += __uint_as_float(wa.y & 0xFFFF0000u);
                a0 += __uint_as_float(wb.x << 16);
                a1 += __uint_as_float(wb.x & 0xFFFF0000u);
                a2 += __uint_as_float(wb.y << 16);
                a3 += __uint_as_float(wb.y & 0xFFFF0000u);
            }
            for (; i < e0; i += 4) {
                unsigned int u = sorted[i];
                uint2 w = Wt2[(size_t)(u & 0x1FFFF) * 16 + ql];
                a0 += __uint_as_float(w.x << 16);
                a1 += __uint_as_float(w.x & 0xFFFF0000u);
                a2 += __uint_as_float(w.y << 16);
                a3 += __uint_as_float(w.y & 0xFFFF0000u);
            }
            // combine the 4 quarters: lanes with equal ql share channels
            a0 += __shfl_xor(a0, 32, 64); a1 += __shfl_xor(a1, 32, 64);
            a2 += __shfl_xor(a2, 32, 64); a3 += __shfl_xor(a3, 32, 64);
            a0 += __shfl_xor(a0, 16, 64); a1 += __shfl_xor(a1, 16, 64);
            a2 += __shfl_xor(a2, 16, 64); a3 += __shfl_xor(a3, 16, 64);

            float x0 = a0 + b0, x1 = a1 + b1, x2 = a2 + b2, x3 = a3 + b3;
            float m = fmaxf(fmaxf(x0, x1), fmaxf(x2, x3));
            for (int off = 8; off > 0; off >>= 1) m = fmaxf(m, __shfl_xor(m, off, 64));
            float ssum = expf(x0 - m) + expf(x1 - m) + expf(x2 - m) + expf(x3 - m);
            for (int off = 8; off > 0; off >>= 1) ssum += __shfl_xor(ssum, off, 64);
            float l = m + logf(ssum);
            if (lane < 16) {
                float4 o = {x0 - l, x1 - l, x2 - l, x3 - l};
                *(float4*)&out[(size_t)gr * OUT_CH + 4 * ql] = o;
            }
        }
    } else {
        // overflow fallback: LDS-atomic accumulate (correct, ~never taken)
        float* acc = (float*)sh;  // 8192 floats = 32 KB
        for (int i = threadIdx.x; i < BROWS * OUT_CH; i += 512) acc[i] = 0.0f;
        __syncthreads();
        for (int i = s + wid; i < e; i += 8) {
            unsigned int u = packed[i];
            float v = __uint_as_float((unsigned int)Wtb[(size_t)(u & 0x1FFFF) * OUT_CH + lane] << 16);
            atomicAdd(&acc[(u >> 17) * OUT_CH + lane], v);
        }
        __syncthreads();
        float bsv = bias[lane];
        for (int r = wid; r < BROWS; r += 8) {
            int gr = b * BROWS + r;
            if (gr >= NUM_NODES) continue;
            float x = acc[r * OUT_CH + lane] + bsv;
            float m = x;
            for (int off = 32; off > 0; off >>= 1) m = fmaxf(m, __shfl_xor(m, off, 64));
            float ex = expf(x - m);
            float ssum = ex;
            for (int off = 32; off > 0; off >>= 1) ssum += __shfl_xor(ssum, off, 64);
            out[(size_t)gr * OUT_CH + lane] = x - m - logf(ssum);
        }
    }
}

// ---------- fallback (round-1 path, direct W) ----------
__global__ void LINK_62689342652831_minf_kernel(const int* __restrict__ rows, int n,
                                                int* __restrict__ minp) {
    int tid = blockIdx.x * blockDim.x + threadIdx.x;
    int stride = gridDim.x * blockDim.x;
    int m = INT_MAX;
    for (int i = tid; i < n; i += stride) m = min(m, rows[i]);
    for (int off = 32; off > 0; off >>= 1) m = min(m, __shfl_xor(m, off, 64));
    if ((threadIdx.x & 63) == 0) atomicMin(minp, m);
}

__global__ void LINK_62689342652831_scatter_kernel(const int* __restrict__ rows,
                                                   const int* __restrict__ cols,
                                                   const float* __restrict__ W,
                                                   const int* __restrict__ minp,
                                                   float* __restrict__ out) {
    int lane = threadIdx.x & 63;
    int gw = (blockIdx.x * blockDim.x + threadIdx.x) >> 6;
    int nw = (gridDim.x * blockDim.x) >> 6;
    int minv = *minp;
    for (int e = gw; e < NUM_EDGES; e += nw) {
        int r = rows[e] - minv;
        int c = cols[e];
        float v = W[(size_t)lane * NUM_NODES + c];
        unsafeAtomicAdd(&out[(size_t)r * 64 + lane], v);
    }
}

__global__ void LINK_62689342652831_logsoftmax_kernel(float* __restrict__ out,
                                                      const float* __restrict__ bias) {
    int lane = threadIdx.x & 63;
    int gw = (blockIdx.x * blockDim.x + threadIdx.x) >> 6;
    int nw = (gridDim.x * blockDim.x) >> 6;
    float b = bias[lane];
    for (int r = gw; r < NUM_NODES; r += nw) {
        float x = out[(size_t)r * 64 + lane] + b;
        float m = x;
        for (int off = 32; off > 0; off >>= 1) m = fmaxf(m, __shfl_xor(m, off, 64));
        float e = expf(x - m);
        float s = e;
        for (int off = 32; off > 0; off >>= 1) s += __shfl_xor(s, off, 64);
        out[(size_t)r * 64 + lane] = x - m - logf(s);
    }
}

extern "C" void kernel_launch(void* const* d_in, const int* in_sizes, int n_in,
                              void* d_out, int out_size, void* d_ws, size_t ws_size,
                              hipStream_t stream) {
    const int* edges = (const int*)d_in[0];
    const int* rows = edges;
    const int* cols = edges + NUM_EDGES;
    const float* W = (const float*)d_in[1];
    const float* bias = (const float*)d_in[2];
    float* out = (float*)d_out;

    // workspace layout
    char* ws = (char*)d_ws;
    const size_t OFF_MIN = 0;                                  // 4 B
    const size_t OFF_BSTART = 256;                             // (NBUCK+1)*4 = 3132 B
    const size_t OFF_TOT = 4096;                               // NBUCK*4 B
    const size_t OFF_H2D = 8192;                               // 256*782*4 = 800768 B
    const size_t OFF_PACKED = 1024 * 1024;                     // 12.8 MB
    const size_t OFF_WTB = OFF_PACKED + (size_t)NUM_EDGES * 4; // 12.8 MB
    const size_t need = OFF_WTB + (size_t)NUM_NODES * OUT_CH * 2;

    int* minp = (int*)(ws + OFF_MIN);
    int* bstart = (int*)(ws + OFF_BSTART);
    int* totals = (int*)(ws + OFF_TOT);
    int* hist2d = (int*)(ws + OFF_H2D);
    unsigned int* packed = (unsigned int*)(ws + OFF_PACKED);
    unsigned short* Wtb = (unsigned short*)(ws + OFF_WTB);

    hipMemsetAsync(minp, 0x7f, sizeof(int), stream);

    if (ws_size >= need) {
        LINK_62689342652831_min_kernel<<<256, 256, 0, stream>>>(rows, minp);
        LINK_62689342652831_transpose_kernel<<<(NUM_NODES + 63) / 64, 256, 0, stream>>>(W, Wtb);
        LINK_62689342652831_hist2d_kernel<<<NPBLK, 512, 0, stream>>>(rows, minp, hist2d);
        LINK_62689342652831_colscan_kernel<<<(NBUCK + 7) / 8, 512, 0, stream>>>(hist2d, totals);
        LINK_62689342652831_bscan_kernel<<<1, 1024, 0, stream>>>(totals, bstart);
        LINK_62689342652831_part_kernel<<<NPBLK, 512, 0, stream>>>(rows, cols, minp, hist2d,
                                                                   bstart, packed);
        LINK_62689342652831_spmm_kernel<<<NBUCK, 512, 0, stream>>>(packed, bstart, Wtb,
                                                                   bias, out);
    } else {
        LINK_62689342652831_minf_kernel<<<2048, 256, 0, stream>>>(rows, NUM_EDGES, minp);
        hipMemsetAsync(d_out, 0, (size_t)out_size * sizeof(float), stream);
        LINK_62689342652831_scatter_kernel<<<2048, 256, 0, stream>>>(rows, cols, W, minp, out);
        LINK_62689342652831_logsoftmax_kernel<<<4096, 256, 0, stream>>>(out, bias);
    }
}